// Round 2
// baseline (376.308 us; speedup 1.0000x reference)
//
#include <hip/hip_runtime.h>
#include <cmath>

// ReadUnit: B=16, K=8192, D=128
//  Im = m_prev@Wim+bim                       [B,D]
//  Ik = knowledge@Wik+bik                    [B,K,D]
//  I  = Im*Ik ; Id = [I|knowledge]@Wid+bid   [B,K,D]
//  cI = c_cur*Id ; ra = cI@Wra+bra           [B,K,D]
//  r  = sum_k softmax_k(ra) * knowledge      [B,D]
// Fused single pass over knowledge with online softmax per (b,d) column.

#define B_ 16
#define K_ 8192
#define D_ 128
#define NCHUNK 128            // chunks per batch -> grid 2048
#define CK (K_ / NCHUNK)      // 64 rows per workgroup
#define TK 32                 // rows per tile
#define LDP 132               // padded LDS leading dim (breaks 32-way bank conflict)

// 4x4 register tile MAC
#define MAC16(A0, A1, A2, A3, W)                  \
  do {                                            \
    acc[0][0] = fmaf((A0), (W).x, acc[0][0]);     \
    acc[0][1] = fmaf((A0), (W).y, acc[0][1]);     \
    acc[0][2] = fmaf((A0), (W).z, acc[0][2]);     \
    acc[0][3] = fmaf((A0), (W).w, acc[0][3]);     \
    acc[1][0] = fmaf((A1), (W).x, acc[1][0]);     \
    acc[1][1] = fmaf((A1), (W).y, acc[1][1]);     \
    acc[1][2] = fmaf((A1), (W).z, acc[1][2]);     \
    acc[1][3] = fmaf((A1), (W).w, acc[1][3]);     \
    acc[2][0] = fmaf((A2), (W).x, acc[2][0]);     \
    acc[2][1] = fmaf((A2), (W).y, acc[2][1]);     \
    acc[2][2] = fmaf((A2), (W).z, acc[2][2]);     \
    acc[2][3] = fmaf((A2), (W).w, acc[2][3]);     \
    acc[3][0] = fmaf((A3), (W).x, acc[3][0]);     \
    acc[3][1] = fmaf((A3), (W).y, acc[3][1]);     \
    acc[3][2] = fmaf((A3), (W).z, acc[3][2]);     \
    acc[3][3] = fmaf((A3), (W).w, acc[3][3]);     \
  } while (0)

__global__ void im_proj_kernel(const float* __restrict__ m_prev,
                               const float* __restrict__ Wim,
                               const float* __restrict__ bim,
                               float* __restrict__ Im) {
  const int b = blockIdx.x;
  const int e = threadIdx.x;
  const float* mp = m_prev + b * D_;
  float acc = 0.f;
#pragma unroll 8
  for (int d = 0; d < D_; ++d) acc = fmaf(mp[d], Wim[d * D_ + e], acc);
  Im[b * D_ + e] = acc + bim[e];
}

__global__ __launch_bounds__(256, 3) void readunit_main(
    const float* __restrict__ c_cur,
    const float* __restrict__ knowledge,
    const float* __restrict__ Wik,
    const float* __restrict__ Wid,
    const float* __restrict__ Wra,
    const float* __restrict__ bik,
    const float* __restrict__ bid,
    const float* __restrict__ bra,
    const float* __restrict__ Im,
    float* __restrict__ partial) {
  __shared__ float s_know[TK][LDP];   // knowledge tile
  __shared__ float s_a[TK][LDP];      // I tile, later ra tile
  __shared__ float s_b[TK][LDP];      // cI tile
  __shared__ float s_merge[3][D_];

  const int wg = blockIdx.x;
  const int b = wg >> 7;            // / NCHUNK
  const int chunk = wg & (NCHUNK - 1);
  const int k0 = chunk * CK;
  const int tid = threadIdx.x;
  const int r0 = (tid >> 5) * 4;    // row block base (0..28 step 4)
  const int col0 = (tid & 31) * 4;  // col block base (0..124 step 4)

  // per-thread broadcast vectors for this thread's 4 output columns
  const float4 im4 = *(const float4*)(Im + b * D_ + col0);
  const float4 c4 = *(const float4*)(c_cur + b * D_ + col0);
  const float4 bik4 = *(const float4*)(bik + col0);
  const float4 bid4 = *(const float4*)(bid + col0);
  const float4 bra4 = *(const float4*)(bra + col0);

  // online-softmax state: thread owns column sd, half of the tile rows
  const int sd = tid & 127;
  const int shalf = tid >> 7;      // 0: rows 0..15, 1: rows 16..31
  float sm = -1e30f, sl = 0.f, sacc = 0.f;

  for (int t = 0; t < CK / TK; ++t) {
    // ---- load knowledge tile (coalesced float4) ----
    const float* gk = knowledge + ((size_t)b * K_ + (size_t)(k0 + t * TK)) * D_;
#pragma unroll
    for (int i = 0; i < 4; ++i) {
      const int flat = tid + 256 * i;   // float4 index within 32x128 tile
      const int row = flat >> 5;        // 32 float4 per row
      const int cc = (flat & 31) * 4;
      *(float4*)(&s_know[row][cc]) = *(const float4*)(gk + row * D_ + cc);
    }
    __syncthreads();

    // ---- stage 1: I = (know @ Wik + bik) * Im ----
    {
      float acc[4][4] = {};
#pragma unroll 8
      for (int kk = 0; kk < D_; ++kk) {
        const float4 w = *(const float4*)(Wik + kk * D_ + col0);
        const float a0 = s_know[r0 + 0][kk];
        const float a1 = s_know[r0 + 1][kk];
        const float a2 = s_know[r0 + 2][kk];
        const float a3 = s_know[r0 + 3][kk];
        MAC16(a0, a1, a2, a3, w);
      }
#pragma unroll
      for (int i = 0; i < 4; ++i) {
        float4 o;
        o.x = (acc[i][0] + bik4.x) * im4.x;
        o.y = (acc[i][1] + bik4.y) * im4.y;
        o.z = (acc[i][2] + bik4.z) * im4.z;
        o.w = (acc[i][3] + bik4.w) * im4.w;
        *(float4*)(&s_a[r0 + i][col0]) = o;
      }
    }
    __syncthreads();

    // ---- stage 2: cI = c_cur * ([I | know] @ Wid + bid) ----
    {
      float acc[4][4] = {};
#pragma unroll 8
      for (int kk = 0; kk < D_; ++kk) {   // I part, Wid rows 0..127
        const float4 w = *(const float4*)(Wid + kk * D_ + col0);
        const float a0 = s_a[r0 + 0][kk];
        const float a1 = s_a[r0 + 1][kk];
        const float a2 = s_a[r0 + 2][kk];
        const float a3 = s_a[r0 + 3][kk];
        MAC16(a0, a1, a2, a3, w);
      }
#pragma unroll 8
      for (int kk = 0; kk < D_; ++kk) {   // knowledge part, Wid rows 128..255
        const float4 w = *(const float4*)(Wid + (D_ + kk) * D_ + col0);
        const float a0 = s_know[r0 + 0][kk];
        const float a1 = s_know[r0 + 1][kk];
        const float a2 = s_know[r0 + 2][kk];
        const float a3 = s_know[r0 + 3][kk];
        MAC16(a0, a1, a2, a3, w);
      }
#pragma unroll
      for (int i = 0; i < 4; ++i) {
        float4 o;
        o.x = c4.x * (acc[i][0] + bid4.x);
        o.y = c4.y * (acc[i][1] + bid4.y);
        o.z = c4.z * (acc[i][2] + bid4.z);
        o.w = c4.w * (acc[i][3] + bid4.w);
        *(float4*)(&s_b[r0 + i][col0]) = o;
      }
    }
    __syncthreads();

    // ---- stage 3: ra = cI @ Wra + bra (into s_a) ----
    // Note: stage 2's barrier already guarantees all reads of s_a are done,
    // so overwriting s_a here needs no extra barrier.
    {
      float acc[4][4] = {};
#pragma unroll 8
      for (int kk = 0; kk < D_; ++kk) {
        const float4 w = *(const float4*)(Wra + kk * D_ + col0);
        const float a0 = s_b[r0 + 0][kk];
        const float a1 = s_b[r0 + 1][kk];
        const float a2 = s_b[r0 + 2][kk];
        const float a3 = s_b[r0 + 3][kk];
        MAC16(a0, a1, a2, a3, w);
      }
#pragma unroll
      for (int i = 0; i < 4; ++i) {
        float4 o;
        o.x = acc[i][0] + bra4.x;
        o.y = acc[i][1] + bra4.y;
        o.z = acc[i][2] + bra4.z;
        o.w = acc[i][3] + bra4.w;
        *(float4*)(&s_a[r0 + i][col0]) = o;
      }
    }
    __syncthreads();

    // ---- stage 4: online softmax update over this tile's rows ----
    {
      const int rbase = shalf * 16;
      float tmax = -1e30f;
#pragma unroll 16
      for (int r = 0; r < 16; ++r) tmax = fmaxf(tmax, s_a[rbase + r][sd]);
      const float mnew = fmaxf(sm, tmax);
      const float scale = __expf(sm - mnew);
      sl *= scale;
      sacc *= scale;
#pragma unroll 16
      for (int r = 0; r < 16; ++r) {
        const float p = __expf(s_a[rbase + r][sd] - mnew);
        sl += p;
        sacc = fmaf(p, s_know[rbase + r][sd], sacc);
      }
      sm = mnew;
    }
    __syncthreads();   // before next tile overwrites s_know / s_a
  }

  // ---- merge the two row-halves, write chunk partial ----
  if (shalf == 1) {
    s_merge[0][sd] = sm;
    s_merge[1][sd] = sl;
    s_merge[2][sd] = sacc;
  }
  __syncthreads();
  if (shalf == 0) {
    const float m1 = s_merge[0][sd], l1 = s_merge[1][sd], a1 = s_merge[2][sd];
    const float ms = fmaxf(sm, m1);
    const float e0 = __expf(sm - ms), e1 = __expf(m1 - ms);
    float* p = partial + (size_t)(b * NCHUNK + chunk) * (3 * D_);
    p[sd] = ms;
    p[D_ + sd] = sl * e0 + l1 * e1;
    p[2 * D_ + sd] = sacc * e0 + a1 * e1;
  }
}

__global__ void readunit_reduce(const float* __restrict__ partial,
                                float* __restrict__ out) {
  const int b = blockIdx.x;
  const int d = threadIdx.x;
  float m = -1e30f, l = 0.f, a = 0.f;
  for (int c = 0; c < NCHUNK; ++c) {
    const float* p = partial + (size_t)(b * NCHUNK + c) * (3 * D_);
    const float mc = p[d], lc = p[D_ + d], ac = p[2 * D_ + d];
    const float mn = fmaxf(m, mc);
    const float s0 = __expf(m - mn), s1 = __expf(mc - mn);
    l = l * s0 + lc * s1;
    a = a * s0 + ac * s1;
    m = mn;
  }
  out[b * D_ + d] = a / l;
}

extern "C" void kernel_launch(void* const* d_in, const int* in_sizes, int n_in,
                              void* d_out, int out_size, void* d_ws, size_t ws_size,
                              hipStream_t stream) {
  const float* c_cur = (const float*)d_in[0];
  const float* m_prev = (const float*)d_in[1];
  const float* knowledge = (const float*)d_in[2];
  const float* Wim = (const float*)d_in[3];
  const float* Wik = (const float*)d_in[4];
  const float* Wid = (const float*)d_in[5];
  const float* Wra = (const float*)d_in[6];
  const float* bim = (const float*)d_in[7];
  const float* bik = (const float*)d_in[8];
  const float* bid = (const float*)d_in[9];
  const float* bra = (const float*)d_in[10];
  float* out = (float*)d_out;

  float* Im = (float*)d_ws;                 // B*D floats
  float* partial = Im + B_ * D_;            // B*NCHUNK*3*D floats (~3 MB)

  im_proj_kernel<<<B_, D_, 0, stream>>>(m_prev, Wim, bim, Im);
  readunit_main<<<B_ * NCHUNK, 256, 0, stream>>>(
      c_cur, knowledge, Wik, Wid, Wra, bik, bid, bra, Im, partial);
  readunit_reduce<<<B_, D_, 0, stream>>>(partial, out);
}

// Round 8
// 161.077 us; speedup vs baseline: 2.3362x; 2.3362x over previous
//
#include <hip/hip_runtime.h>
#include <cmath>

// ReadUnit, MFMA version. B=16, K=8192, D=128.
//  Im = m_prev@Wim+bim                      [B,D]    (fp32 mini-kernel)
//  I  = (know@Wik+bik)*Im                   [B,K,D]  stage 1 (MFMA)
//  cI = c_cur*([I|know]@Wid+bid)            [B,K,D]  stage 2 (MFMA)
//  ra = cI@Wra+bra                          [B,K,D]  stage 3 (MFMA)
//  r  = sum_k softmax_k(ra)*know            [B,D]    online softmax on C-frags
// Precision: activations bf16(hi), weights bf16 hi+lo (2 MFMAs), fp32 accum.

#define B_ 16
#define K_ 8192
#define D_ 128
#define CK 128                 // rows per workgroup
#define NCHUNK (K_ / CK)       // 64
#define TR 32                  // rows per row-tile
#define NT (CK / TR)           // 4
#define LDP 136                // LDS row stride in bf16 elems (272B: 16B-mult, 2-way banks only)

typedef __attribute__((ext_vector_type(8))) short short8;
typedef __attribute__((ext_vector_type(4))) float f32x4;

__device__ __forceinline__ unsigned short f2bf(float x) {
  unsigned int u = __float_as_uint(x);
  u = (u + 0x7fffu + ((u >> 16) & 1u)) >> 16;   // RNE
  return (unsigned short)u;
}
__device__ __forceinline__ float bf2f(unsigned short h) {
  return __uint_as_float(((unsigned int)h) << 16);
}

// ---- pack weights into MFMA B-fragment order, bf16 hi/lo planes ----
// frag id F = (QQ*8 + nfrag)*2 + h ; QQ: 0-3 Wik, 4-11 Wid, 12-15 Wra.
// B-frag elem: lane l, j=0..7 -> B[k=32q+(l>>4)*8+j][col=16n+(l&15)]
__global__ void pack_weights(const float* __restrict__ Wik,
                             const float* __restrict__ Wid,
                             const float* __restrict__ Wra,
                             unsigned short* __restrict__ packed) {
  const int F = blockIdx.x;      // 0..255
  const int l = threadIdx.x;     // 0..63
  const int h = F & 1;
  const int n = (F >> 1) & 7;
  const int QQ = F >> 4;
  const float* W; int q;
  if (QQ < 4)       { W = Wik; q = QQ; }
  else if (QQ < 12) { W = Wid; q = QQ - 4; }
  else              { W = Wra; q = QQ - 12; }
  const int col = n * 16 + (l & 15);
  const int kb = q * 32 + (l >> 4) * 8;
  unsigned short* dst = packed + (size_t)F * 512 + l * 8;
#pragma unroll
  for (int j = 0; j < 8; ++j) {
    const float v = W[(kb + j) * D_ + col];
    const unsigned short hi = f2bf(v);
    dst[j] = h ? f2bf(v - bf2f(hi)) : hi;
  }
}

__global__ void im_proj_kernel(const float* __restrict__ m_prev,
                               const float* __restrict__ Wim,
                               const float* __restrict__ bim,
                               float* __restrict__ Im) {
  const int b = blockIdx.x;
  const int e = threadIdx.x;
  const float* mp = m_prev + b * D_;
  float acc = 0.f;
#pragma unroll 8
  for (int d = 0; d < D_; ++d) acc = fmaf(mp[d], Wim[d * D_ + e], acc);
  Im[b * D_ + e] = acc + bim[e];
}

__global__ __launch_bounds__(256, 2) void readunit_main(
    const float* __restrict__ c_cur,
    const float* __restrict__ knowledge,
    const float* __restrict__ bik,
    const float* __restrict__ bid,
    const float* __restrict__ bra,
    const float* __restrict__ Im,
    const unsigned short* __restrict__ packed,
    float* __restrict__ partial) {
  __shared__ unsigned short know_h[CK * LDP];  // 34816 B
  __shared__ unsigned short I_h[CK * LDP];     // 34816 B (reused as cI)

  const int chunk = blockIdx.x;
  const int b = blockIdx.y;
  const int tid = threadIdx.x;
  const int lane = tid & 63;
  const int wn = tid >> 6;       // wave id = column-split 0..3 (cols 32*wn..+31)
  const int lr = lane & 15;
  const int lg = lane >> 4;

  // ---- phase 0: stage knowledge chunk (bf16 hi) ----
  const float* gk = knowledge + ((size_t)b * K_ + (size_t)chunk * CK) * D_;
#pragma unroll
  for (int i = 0; i < 16; ++i) {
    const int flat = tid + 256 * i;
    const int row = flat >> 5;
    const int c4 = (flat & 31) * 4;
    const float4 v = *(const float4*)(gk + row * D_ + c4);
    ushort4 hv;
    hv.x = f2bf(v.x); hv.y = f2bf(v.y); hv.z = f2bf(v.z); hv.w = f2bf(v.w);
    *(ushort4*)(&know_h[row * LDP + c4]) = hv;
  }

  float imv[2], cv[2], bikv[2], bidv[2], brav[2];
#pragma unroll
  for (int f = 0; f < 2; ++f) {
    const int col = wn * 32 + f * 16 + lr;
    imv[f]  = Im[b * D_ + col];
    cv[f]   = c_cur[b * D_ + col];
    bikv[f] = bik[col];
    bidv[f] = bid[col];
    brav[f] = bra[col];
  }
  __syncthreads();

  short8 Bf[2][8][2];  // [nfrag][kchunk][hi/lo] weight fragments, per stage

  // ---- phase 1: I = (know@Wik+bik)*Im -> I_h ----
#pragma unroll
  for (int q = 0; q < 4; ++q)
#pragma unroll
    for (int f = 0; f < 2; ++f)
#pragma unroll
      for (int h = 0; h < 2; ++h) {
        const int F = (q * 8 + (wn * 2 + f)) * 2 + h;
        Bf[f][q][h] = *(const short8*)(packed + (size_t)F * 512 + lane * 8);
      }
  for (int t = 0; t < NT; ++t) {
    const int rb = t * TR;
    f32x4 acc[2][2] = {};
#pragma unroll
    for (int q = 0; q < 4; ++q) {
      const short8 a0 = *(const short8*)(&know_h[(rb + lr) * LDP + q * 32 + lg * 8]);
      const short8 a1 = *(const short8*)(&know_h[(rb + 16 + lr) * LDP + q * 32 + lg * 8]);
#pragma unroll
      for (int f = 0; f < 2; ++f) {
        acc[0][f] = __builtin_amdgcn_mfma_f32_16x16x32_bf16(a0, Bf[f][q][0], acc[0][f], 0, 0, 0);
        acc[0][f] = __builtin_amdgcn_mfma_f32_16x16x32_bf16(a0, Bf[f][q][1], acc[0][f], 0, 0, 0);
        acc[1][f] = __builtin_amdgcn_mfma_f32_16x16x32_bf16(a1, Bf[f][q][0], acc[1][f], 0, 0, 0);
        acc[1][f] = __builtin_amdgcn_mfma_f32_16x16x32_bf16(a1, Bf[f][q][1], acc[1][f], 0, 0, 0);
      }
    }
#pragma unroll
    for (int m = 0; m < 2; ++m)
#pragma unroll
      for (int f = 0; f < 2; ++f) {
        const int col = wn * 32 + f * 16 + lr;
#pragma unroll
        for (int r = 0; r < 4; ++r) {
          const int row = rb + m * 16 + lg * 4 + r;
          I_h[row * LDP + col] = f2bf((acc[m][f][r] + bikv[f]) * imv[f]);
        }
      }
  }
  __syncthreads();

  // ---- phase 2: cI = c_cur*([I|know]@Wid+bid) -> overwrite I_h tile-wise ----
#pragma unroll
  for (int q = 0; q < 8; ++q)
#pragma unroll
    for (int f = 0; f < 2; ++f)
#pragma unroll
      for (int h = 0; h < 2; ++h) {
        const int F = ((4 + q) * 8 + (wn * 2 + f)) * 2 + h;
        Bf[f][q][h] = *(const short8*)(packed + (size_t)F * 512 + lane * 8);
      }
  for (int t = 0; t < NT; ++t) {
    const int rb = t * TR;
    f32x4 acc[2][2] = {};
#pragma unroll
    for (int q = 0; q < 8; ++q) {
      const unsigned short* src = (q < 4)
          ? &I_h[(rb + lr) * LDP + q * 32 + lg * 8]
          : &know_h[(rb + lr) * LDP + (q - 4) * 32 + lg * 8];
      const short8 a0 = *(const short8*)(src);
      const short8 a1 = *(const short8*)(src + 16 * LDP);
#pragma unroll
      for (int f = 0; f < 2; ++f) {
        acc[0][f] = __builtin_amdgcn_mfma_f32_16x16x32_bf16(a0, Bf[f][q][0], acc[0][f], 0, 0, 0);
        acc[0][f] = __builtin_amdgcn_mfma_f32_16x16x32_bf16(a0, Bf[f][q][1], acc[0][f], 0, 0, 0);
        acc[1][f] = __builtin_amdgcn_mfma_f32_16x16x32_bf16(a1, Bf[f][q][0], acc[1][f], 0, 0, 0);
        acc[1][f] = __builtin_amdgcn_mfma_f32_16x16x32_bf16(a1, Bf[f][q][1], acc[1][f], 0, 0, 0);
      }
    }
    __syncthreads();   // all waves finished reading tile t of I_h
#pragma unroll
    for (int m = 0; m < 2; ++m)
#pragma unroll
      for (int f = 0; f < 2; ++f) {
        const int col = wn * 32 + f * 16 + lr;
#pragma unroll
        for (int r = 0; r < 4; ++r) {
          const int row = rb + m * 16 + lg * 4 + r;
          I_h[row * LDP + col] = f2bf(cv[f] * (acc[m][f][r] + bidv[f]));
        }
      }
    // next tile reads disjoint rows; no barrier needed here
  }
  __syncthreads();

  // ---- phase 3: ra = cI@Wra+bra ; online softmax on C-fragments ----
#pragma unroll
  for (int q = 0; q < 4; ++q)
#pragma unroll
    for (int f = 0; f < 2; ++f)
#pragma unroll
      for (int h = 0; h < 2; ++h) {
        const int F = ((12 + q) * 8 + (wn * 2 + f)) * 2 + h;
        Bf[f][q][h] = *(const short8*)(packed + (size_t)F * 512 + lane * 8);
      }
  float sm[2] = {-1e30f, -1e30f}, sl[2] = {0.f, 0.f}, sacc[2] = {0.f, 0.f};
  for (int t = 0; t < NT; ++t) {
    const int rb = t * TR;
    f32x4 acc[2][2] = {};
#pragma unroll
    for (int q = 0; q < 4; ++q) {
      const short8 a0 = *(const short8*)(&I_h[(rb + lr) * LDP + q * 32 + lg * 8]);
      const short8 a1 = *(const short8*)(&I_h[(rb + 16 + lr) * LDP + q * 32 + lg * 8]);
#pragma unroll
      for (int f = 0; f < 2; ++f) {
        acc[0][f] = __builtin_amdgcn_mfma_f32_16x16x32_bf16(a0, Bf[f][q][0], acc[0][f], 0, 0, 0);
        acc[0][f] = __builtin_amdgcn_mfma_f32_16x16x32_bf16(a0, Bf[f][q][1], acc[0][f], 0, 0, 0);
        acc[1][f] = __builtin_amdgcn_mfma_f32_16x16x32_bf16(a1, Bf[f][q][0], acc[1][f], 0, 0, 0);
        acc[1][f] = __builtin_amdgcn_mfma_f32_16x16x32_bf16(a1, Bf[f][q][1], acc[1][f], 0, 0, 0);
      }
    }
#pragma unroll
    for (int f = 0; f < 2; ++f) {
      const int col = wn * 32 + f * 16 + lr;
      float v[8];
#pragma unroll
      for (int m = 0; m < 2; ++m)
#pragma unroll
        for (int r = 0; r < 4; ++r) v[m * 4 + r] = acc[m][f][r] + brav[f];
      float tmax = v[0];
#pragma unroll
      for (int i = 1; i < 8; ++i) tmax = fmaxf(tmax, v[i]);
      const float mnew = fmaxf(sm[f], tmax);
      const float scale = __expf(sm[f] - mnew);
      sl[f] *= scale;
      sacc[f] *= scale;
#pragma unroll
      for (int m = 0; m < 2; ++m)
#pragma unroll
        for (int r = 0; r < 4; ++r) {
          const int row = rb + m * 16 + lg * 4 + r;
          const float p = __expf(v[m * 4 + r] - mnew);
          sl[f] += p;
          sacc[f] = fmaf(p, bf2f(know_h[row * LDP + col]), sacc[f]);
        }
      sm[f] = mnew;
    }
  }

  // ---- merge across the 4 lane-groups (rows), write chunk partial ----
#pragma unroll
  for (int f = 0; f < 2; ++f) {
#pragma unroll
    for (int s = 0; s < 2; ++s) {
      const int off = (s == 0) ? 16 : 32;
      const float om = __shfl_xor(sm[f], off);
      const float ol = __shfl_xor(sl[f], off);
      const float oa = __shfl_xor(sacc[f], off);
      const float mn = fmaxf(sm[f], om);
      const float e0 = __expf(sm[f] - mn), e1 = __expf(om - mn);
      sl[f] = sl[f] * e0 + ol * e1;
      sacc[f] = sacc[f] * e0 + oa * e1;
      sm[f] = mn;
    }
  }
  if (lg == 0) {
    float* p = partial + (size_t)(b * NCHUNK + chunk) * (3 * D_);
#pragma unroll
    for (int f = 0; f < 2; ++f) {
      const int col = wn * 32 + f * 16 + lr;
      p[col] = sm[f];
      p[D_ + col] = sl[f];
      p[2 * D_ + col] = sacc[f];
    }
  }
}

__global__ void readunit_reduce(const float* __restrict__ partial,
                                float* __restrict__ out) {
  const int b = blockIdx.x;
  const int d = threadIdx.x;
  float m = -1e30f, l = 0.f, a = 0.f;
  for (int c = 0; c < NCHUNK; ++c) {
    const float* p = partial + (size_t)(b * NCHUNK + c) * (3 * D_);
    const float mc = p[d], lc = p[D_ + d], ac = p[2 * D_ + d];
    const float mn = fmaxf(m, mc);
    const float s0 = __expf(m - mn), s1 = __expf(mc - mn);
    l = l * s0 + lc * s1;
    a = a * s0 + ac * s1;
    m = mn;
  }
  out[b * D_ + d] = a / l;
}

extern "C" void kernel_launch(void* const* d_in, const int* in_sizes, int n_in,
                              void* d_out, int out_size, void* d_ws, size_t ws_size,
                              hipStream_t stream) {
  const float* c_cur = (const float*)d_in[0];
  const float* m_prev = (const float*)d_in[1];
  const float* knowledge = (const float*)d_in[2];
  const float* Wim = (const float*)d_in[3];
  const float* Wik = (const float*)d_in[4];
  const float* Wid = (const float*)d_in[5];
  const float* Wra = (const float*)d_in[6];
  const float* bim = (const float*)d_in[7];
  const float* bik = (const float*)d_in[8];
  const float* bid = (const float*)d_in[9];
  const float* bra = (const float*)d_in[10];
  float* out = (float*)d_out;

  float* Im = (float*)d_ws;                            // 2048 floats
  float* partial = Im + B_ * D_;                       // 16*64*384 floats (~1.5 MB)
  unsigned short* packed =
      (unsigned short*)(partial + (size_t)B_ * NCHUNK * 3 * D_);  // 256 KB

  pack_weights<<<256, 64, 0, stream>>>(Wik, Wid, Wra, packed);
  im_proj_kernel<<<B_, D_, 0, stream>>>(m_prev, Wim, bim, Im);
  readunit_main<<<dim3(NCHUNK, B_), 256, 0, stream>>>(
      c_cur, knowledge, bik, bid, bra, Im, packed, partial);
  readunit_reduce<<<B_, D_, 0, stream>>>(partial, out);
}